// Round 4
// baseline (578.641 us; speedup 1.0000x reference)
//
#include <hip/hip_runtime.h>
#include <math.h>

// EMRouting: B=8,H=12,W=12,K=3,CIN=16,COUT=32,P=16 -> 1152 positions x 144 votes
#define NPOS 1152
#define NN   144
#define COUTC 32
#define PP   16
#define EPSF 1e-7f
#define LOG2PI 1.8378770664093453f

#define MU_OFF   0
#define A_OFF    589824            // 1152*32*16
#define SIG_OFF  626688            // + 1152*32

typedef __attribute__((ext_vector_type(2))) __fp16    half2v;
typedef __attribute__((ext_vector_type(4))) float     f32x4;
typedef __attribute__((ext_vector_type(4))) unsigned  u32x4;

static __device__ __forceinline__ unsigned pk2(float a, float b) {
    half2v h = __builtin_amdgcn_cvt_pkrtz(a, b);   // v_cvt_pkrtz_f16_f32
    return __builtin_bit_cast(unsigned, h);
}
static __device__ __forceinline__ void unpk2(unsigned u, float& a, float& b) {
    half2v h = __builtin_bit_cast(half2v, u);
    a = (float)h.x; b = (float)h.y;
}

// Block = 256 threads = 4 waves. cout = tid&31, slot = tid>>5 (8 n-slots, n = slot+8j).
// Softmax over cout: 32-lane shuffle. Pass 1 reads fp32 V non-temporally and writes an
// fp16 copy to ws; passes 2-3 read the fp16 copy (162 MB -> mostly L3-resident).
template<int USE_HALF>
__global__ void __launch_bounds__(256)
em_routing_kernel(const float* __restrict__ V,
                  const float* __restrict__ a,
                  const float* __restrict__ Bu,
                  const float* __restrict__ Ba,
                  const float* __restrict__ Rin,
                  float* __restrict__ out,
                  u32x4* __restrict__ Vh)
{
    const int pos  = blockIdx.x;
    const int tid  = threadIdx.x;
    const int c    = tid & 31;
    const int slot = tid >> 5;
    const int wave = tid >> 6;

    const float* Vp = V + (size_t)pos * (NN * COUTC * PP);
    const float* Rp = Rin + (size_t)pos * (NN * COUTC);

    __shared__ float a_s[NN];
    __shared__ float red[4][COUTC][33];  // [0]=S0, [1..16]=S1, [17..32]=S2
    __shared__ float fin[COUTC][33];
    __shared__ float mu_s[COUTC][17];
    __shared__ float wp_s[COUTC][17];    // 1/(2*sigma^2+EPS)
    __shared__ float sg_s[COUTC][17];
    __shared__ float cl_s[COUTC];        // log(a_out) + log_p1
    __shared__ float ao_s[COUTC];

    for (int i = tid; i < NN; i += 256) a_s[i] = a[pos * NN + i];
    __syncthreads();

    const float lam_tab[3] = {0.01f * (1.f - 0.95f),
                              0.01f * (1.f - 0.95f * 0.95f),
                              0.01f * (1.f - 0.95f * 0.95f * 0.95f)};

    // ---- shared reduce + per-cout finalize (3 barriers) ----
    auto reduce_finalize = [&](int it, float S0, float (&S1)[PP], float (&S2)[PP]) {
        S0 += __shfl_xor(S0, 32, 64);
        #pragma unroll
        for (int p = 0; p < PP; ++p) {
            S1[p] += __shfl_xor(S1[p], 32, 64);
            S2[p] += __shfl_xor(S2[p], 32, 64);
        }
        if ((tid & 32) == 0) {
            red[wave][c][0] = S0;
            #pragma unroll
            for (int p = 0; p < PP; ++p) {
                red[wave][c][1 + p]  = S1[p];
                red[wave][c][17 + p] = S2[p];
            }
        }
        __syncthreads();
        for (int idx = tid; idx < COUTC * 33; idx += 256) {
            int cc = idx / 33, k = idx - cc * 33;
            fin[cc][k] = red[0][cc][k] + red[1][cc][k] + red[2][cc][k] + red[3][cc][k];
        }
        __syncthreads();
        if (tid < 64) {                       // wave 0 does the whole finalize
            float xv = 0.f, sumlog = 0.f;
            if (tid < 32) {
                const int cc = tid;
                float d0  = fin[cc][0];
                float inv = 1.f / (d0 + EPSF);
                #pragma unroll
                for (int p = 0; p < PP; ++p) {
                    float s1 = fin[cc][1 + p];
                    float s2 = fin[cc][17 + p];
                    float mu = s1 * inv;
                    float sg = (s2 - 2.f * mu * s1 + mu * mu * d0) * inv;
                    sg = fmaxf(sg, 1e-30f);   // guard cancellation
                    mu_s[cc][p] = mu;
                    sg_s[cc][p] = sg;
                    wp_s[cc][p] = 1.f / (2.f * sg + EPSF);
                    sumlog += logf(sg);
                }
                xv = lam_tab[it] * (Ba[cc] - d0 * (16.f * Bu[cc] + 0.5f * sumlog));
            }
            float ss = xv * xv;               // L2 norm over cout (upper lanes add 0)
            #pragma unroll
            for (int m = 1; m <= 32; m <<= 1) ss += __shfl_xor(ss, m, 64);
            if (tid < 32) {
                float y  = xv / fmaxf(sqrtf(ss), 1e-12f);
                float ao = 1.f / (1.f + expf(-y));
                ao_s[tid] = ao;
                cl_s[tid] = logf(ao) - 0.5f * (16.f * LOG2PI + sumlog) + EPSF;
            }
        }
        __syncthreads();
    };

    // ---- pass 0: R from input; stream fp32 V (non-temporal), emit fp16 copy ----
    {
        float S0 = 0.f, S1[PP], S2[PP];
        #pragma unroll
        for (int p = 0; p < PP; ++p) { S1[p] = 0.f; S2[p] = 0.f; }

        #pragma unroll 3
        for (int j = 0; j < 18; ++j) {
            const int n = slot + (j << 3);
            const f32x4* vp = (const f32x4*)(Vp + (size_t)n * (COUTC * PP) + c * PP);
            f32x4 q0 = __builtin_nontemporal_load(vp);
            f32x4 q1 = __builtin_nontemporal_load(vp + 1);
            f32x4 q2 = __builtin_nontemporal_load(vp + 2);
            f32x4 q3 = __builtin_nontemporal_load(vp + 3);
            float v[PP] = {q0.x,q0.y,q0.z,q0.w, q1.x,q1.y,q1.z,q1.w,
                           q2.x,q2.y,q2.z,q2.w, q3.x,q3.y,q3.z,q3.w};
            if (USE_HALF) {
                size_t hb = ((size_t)(pos * NN + n) << 6) + (c << 1); // u32x4 units
                u32x4 u0, u1;
                u0.x = pk2(v[0],  v[1]);  u0.y = pk2(v[2],  v[3]);
                u0.z = pk2(v[4],  v[5]);  u0.w = pk2(v[6],  v[7]);
                u1.x = pk2(v[8],  v[9]);  u1.y = pk2(v[10], v[11]);
                u1.z = pk2(v[12], v[13]); u1.w = pk2(v[14], v[15]);
                Vh[hb] = u0; Vh[hb + 1] = u1;   // temporal: want these in L2/L3
            }
            float Rw = __builtin_nontemporal_load(Rp + n * COUTC + c) * a_s[n];
            S0 += Rw;
            #pragma unroll
            for (int p = 0; p < PP; ++p) {
                float t = Rw * v[p];
                S1[p] += t;
                S2[p] = fmaf(t, v[p], S2[p]);
            }
        }
        reduce_finalize(0, S0, S1, S2);
    }

    // ---- passes 1,2: E-step softmax fused with next M-step ----
    for (int it = 1; it < 3; ++it) {
        float mu_r[PP], wp_r[PP];
        #pragma unroll
        for (int p = 0; p < PP; ++p) { mu_r[p] = mu_s[c][p]; wp_r[p] = wp_s[c][p]; }
        float cl_r = cl_s[c];
        // pin the per-lane constants into VGPRs (stop LDS rematerialization)
        #pragma unroll
        for (int p = 0; p < PP; ++p) {
            asm volatile("" : "+v"(mu_r[p]), "+v"(wp_r[p]));
        }
        asm volatile("" : "+v"(cl_r));

        float S0 = 0.f, S1[PP], S2[PP];
        #pragma unroll
        for (int p = 0; p < PP; ++p) { S1[p] = 0.f; S2[p] = 0.f; }

        for (int j = 0; j < 18; ++j) {
            const int n = slot + (j << 3);
            float v[PP];
            if (USE_HALF) {
                size_t hb = ((size_t)(pos * NN + n) << 6) + (c << 1);
                u32x4 u0 = Vh[hb], u1 = Vh[hb + 1];
                unsigned uu[8] = {u0.x, u0.y, u0.z, u0.w, u1.x, u1.y, u1.z, u1.w};
                #pragma unroll
                for (int k = 0; k < 8; ++k) unpk2(uu[k], v[2 * k], v[2 * k + 1]);
            } else {
                const f32x4* vp = (const f32x4*)(Vp + (size_t)n * (COUTC * PP) + c * PP);
                f32x4 q0 = vp[0], q1 = vp[1], q2 = vp[2], q3 = vp[3];
                v[0]=q0.x; v[1]=q0.y; v[2]=q0.z; v[3]=q0.w;
                v[4]=q1.x; v[5]=q1.y; v[6]=q1.z; v[7]=q1.w;
                v[8]=q2.x; v[9]=q2.y; v[10]=q2.z; v[11]=q2.w;
                v[12]=q3.x; v[13]=q3.y; v[14]=q3.z; v[15]=q3.w;
            }
            float acc = 0.f;
            #pragma unroll
            for (int p = 0; p < PP; ++p) {
                float d = v[p] - mu_r[p];
                acc = fmaf(d * wp_r[p], d, acc);
            }
            float logit = cl_r - acc;
            float m = logit;
            #pragma unroll
            for (int msk = 1; msk <= 16; msk <<= 1)
                m = fmaxf(m, __shfl_xor(m, msk, 64));
            float e = __expf(logit - m);
            float sum = e;
            #pragma unroll
            for (int msk = 1; msk <= 16; msk <<= 1)
                sum += __shfl_xor(sum, msk, 64);
            float Rw = (e / sum) * a_s[n];
            S0 += Rw;
            #pragma unroll
            for (int p = 0; p < PP; ++p) {
                float t = Rw * v[p];
                S1[p] += t;
                S2[p] = fmaf(t, v[p], S2[p]);
            }
        }
        reduce_finalize(it, S0, S1, S2);
    }

    // ---- outputs (from iteration 2's M-step) ----
    for (int idx = tid; idx < COUTC * PP; idx += 256) {
        int cc = idx >> 4, p = idx & 15;
        out[MU_OFF  + (size_t)pos * (COUTC * PP) + idx] = mu_s[cc][p];
        out[SIG_OFF + (size_t)pos * (COUTC * PP) + idx] = sg_s[cc][p];
    }
    if (tid < COUTC) out[A_OFF + pos * COUTC + tid] = ao_s[tid];
}

extern "C" void kernel_launch(void* const* d_in, const int* in_sizes, int n_in,
                              void* d_out, int out_size, void* d_ws, size_t ws_size,
                              hipStream_t stream) {
    const float* V  = (const float*)d_in[0];
    const float* a  = (const float*)d_in[1];
    const float* Bu = (const float*)d_in[2];
    const float* Ba = (const float*)d_in[3];
    const float* R  = (const float*)d_in[4];
    float* out = (float*)d_out;
    const size_t need = (size_t)NPOS * NN * COUTC * PP * 2;   // 162 MB fp16 V copy
    if (ws_size >= need) {
        em_routing_kernel<1><<<NPOS, 256, 0, stream>>>(V, a, Bu, Ba, R, out, (u32x4*)d_ws);
    } else {
        em_routing_kernel<0><<<NPOS, 256, 0, stream>>>(V, a, Bu, Ba, R, out, (u32x4*)d_ws);
    }
}